// Round 2
// baseline (654.797 us; speedup 1.0000x reference)
//
#include <hip/hip_runtime.h>
#include <math.h>

// Keep fp32 arithmetic un-contracted so results track the numpy/JAX reference
// bit-closely (argmin tie safety on the face-index output).
#pragma clang fp contract(off)

namespace {

constexpr int B = 2;
constexpr int F = 4096;      // triangles per batch
constexpr int Q = 16384;     // points per batch
constexpr int NP = B * Q;    // 32768 total points
constexpr int NCHUNK = 8;    // triangle chunks
constexpr int CF = F / NCHUNK;  // 512 triangles per chunk
constexpr int BLOCK = 256;

// output layout in d_out (float32):
//   dist    [B*Q]      at offset 0
//   closest [B*Q*3]    at offset NP
//   faces   [B*Q]      at offset NP + 3*NP  (written as float values)
constexpr int OFF_DIST = 0;
constexpr int OFF_CP = NP;
constexpr int OFF_FACE = NP + 3 * NP;

__device__ __forceinline__ float safediv(float num, float den) {
  float d = (fabsf(den) > 1e-12f) ? den : 1.0f;
  return num / d;
}

__device__ __forceinline__ float clamp01(float x) {
  return fminf(fmaxf(x, 0.0f), 1.0f);
}

// Ericson region-based closest point on triangle, mirroring the JAX reference
// op-for-op (including the where/override order).
__device__ __forceinline__ void closest_pt(
    float px, float py, float pz,
    float ax, float ay, float az,
    float bx, float by, float bz,
    float cx, float cy, float cz,
    float& rx, float& ry, float& rz) {
  float abx = bx - ax, aby = by - ay, abz = bz - az;
  float acx = cx - ax, acy = cy - ay, acz = cz - az;
  float apx = px - ax, apy = py - ay, apz = pz - az;
  float d1 = (abx * apx + aby * apy) + abz * apz;
  float d2 = (acx * apx + acy * apy) + acz * apz;
  float bpx = px - bx, bpy = py - by, bpz = pz - bz;
  float d3 = (abx * bpx + aby * bpy) + abz * bpz;
  float d4 = (acx * bpx + acy * bpy) + acz * bpz;
  float cpx = px - cx, cpy = py - cy, cpz = pz - cz;
  float d5 = (abx * cpx + aby * cpy) + abz * cpz;
  float d6 = (acx * cpx + acy * cpy) + acz * cpz;

  float vc = d1 * d4 - d3 * d2;
  float vb = d5 * d2 - d1 * d6;
  float va = d3 * d6 - d5 * d4;

  float v_ab = clamp01(safediv(d1, d1 - d3));
  float w_ac = clamp01(safediv(d2, d2 - d6));
  float w_bc = clamp01(safediv(d4 - d3, (d4 - d3) + (d5 - d6)));

  float denom = (va + vb) + vc;
  float v = safediv(vb, denom);
  float w = safediv(vc, denom);

  // interior (default)
  float ox = ax + abx * v + acx * w;
  float oy = ay + aby * v + acy * w;
  float oz = az + abz * v + acz * w;

  bool m_bc = (va <= 0.0f) && (d4 - d3 >= 0.0f) && (d5 - d6 >= 0.0f);
  bool m_ac = (vb <= 0.0f) && (d2 >= 0.0f) && (d6 <= 0.0f);
  bool m_ab = (vc <= 0.0f) && (d1 >= 0.0f) && (d3 <= 0.0f);
  bool m_c  = (d6 >= 0.0f) && (d5 <= d6);
  bool m_b  = (d3 >= 0.0f) && (d4 <= d3);
  bool m_a  = (d1 <= 0.0f) && (d2 <= 0.0f);

  // later overrides earlier, same order as the reference's jnp.where chain
  if (m_bc) { ox = bx + w_bc * (cx - bx); oy = by + w_bc * (cy - by); oz = bz + w_bc * (cz - bz); }
  if (m_ac) { ox = ax + w_ac * acx;       oy = ay + w_ac * acy;       oz = az + w_ac * acz; }
  if (m_ab) { ox = ax + v_ab * abx;       oy = ay + v_ab * aby;       oz = az + v_ab * abz; }
  if (m_c)  { ox = cx; oy = cy; oz = cz; }
  if (m_b)  { ox = bx; oy = by; oz = bz; }
  if (m_a)  { ox = ax; oy = ay; oz = az; }

  rx = ox; ry = oy; rz = oz;
}

__global__ __launch_bounds__(BLOCK) void bvh_partial(
    const float* __restrict__ tris,   // [B, F, 3, 3]
    const float* __restrict__ pts,    // [B, Q, 3]
    float* __restrict__ dpart,        // [NCHUNK, NP]
    int* __restrict__ ipart) {        // [NCHUNK, NP]
  __shared__ float s_tri[CF * 9];     // 18 KiB

  const int chunk = blockIdx.y;
  const int gpt = blockIdx.x * BLOCK + threadIdx.x;  // 0 .. NP-1
  const int batch = gpt / Q;  // BLOCK divides Q, so uniform per block

  // stage this chunk's triangles into LDS (coalesced)
  const float* tbase = tris + ((size_t)batch * F + (size_t)chunk * CF) * 9;
  for (int i = threadIdx.x; i < CF * 9; i += BLOCK) s_tri[i] = tbase[i];
  __syncthreads();

  const float px = pts[gpt * 3 + 0];
  const float py = pts[gpt * 3 + 1];
  const float pz = pts[gpt * 3 + 2];

  float best = INFINITY;
  int bi = 0;
  for (int t = 0; t < CF; ++t) {
    const float* tr = &s_tri[t * 9];
    float rx, ry, rz;
    closest_pt(px, py, pz,
               tr[0], tr[1], tr[2],
               tr[3], tr[4], tr[5],
               tr[6], tr[7], tr[8],
               rx, ry, rz);
    float dx = px - rx, dy = py - ry, dz = pz - rz;
    float dd = (dx * dx + dy * dy) + dz * dz;
    if (dd < best) { best = dd; bi = t; }   // strict <: first-occurrence argmin
  }

  dpart[chunk * NP + gpt] = best;
  ipart[chunk * NP + gpt] = chunk * CF + bi;
}

__global__ __launch_bounds__(BLOCK) void bvh_reduce(
    const float* __restrict__ tris,
    const float* __restrict__ pts,
    const float* __restrict__ dpart,
    const int* __restrict__ ipart,
    float* __restrict__ out) {
  const int gpt = blockIdx.x * BLOCK + threadIdx.x;
  if (gpt >= NP) return;

  float best = INFINITY;
  int bi = 0;
  for (int c = 0; c < NCHUNK; ++c) {   // ascending chunk order keeps earliest face on ties
    float d = dpart[c * NP + gpt];
    if (d < best) { best = d; bi = ipart[c * NP + gpt]; }
  }

  const int batch = gpt / Q;
  const float px = pts[gpt * 3 + 0];
  const float py = pts[gpt * 3 + 1];
  const float pz = pts[gpt * 3 + 2];

  const float* tr = tris + ((size_t)batch * F + bi) * 9;
  float rx, ry, rz;
  closest_pt(px, py, pz,
             tr[0], tr[1], tr[2],
             tr[3], tr[4], tr[5],
             tr[6], tr[7], tr[8],
             rx, ry, rz);

  out[OFF_DIST + gpt] = best;
  out[OFF_CP + gpt * 3 + 0] = rx;
  out[OFF_CP + gpt * 3 + 1] = ry;
  out[OFF_CP + gpt * 3 + 2] = rz;
  out[OFF_FACE + gpt] = (float)bi;   // harness reads whole out buffer as f32
}

}  // namespace

extern "C" void kernel_launch(void* const* d_in, const int* in_sizes, int n_in,
                              void* d_out, int out_size, void* d_ws, size_t ws_size,
                              hipStream_t stream) {
  const float* tris = (const float*)d_in[0];
  const float* pts  = (const float*)d_in[1];
  float* out = (float*)d_out;

  float* dpart = (float*)d_ws;                          // NCHUNK*NP floats = 1 MiB
  int* ipart = (int*)((char*)d_ws + sizeof(float) * NCHUNK * NP);  // 1 MiB

  dim3 grid1(NP / BLOCK, NCHUNK);   // 128 x 8 blocks
  bvh_partial<<<grid1, BLOCK, 0, stream>>>(tris, pts, dpart, ipart);

  dim3 grid2((NP + BLOCK - 1) / BLOCK);
  bvh_reduce<<<grid2, BLOCK, 0, stream>>>(tris, pts, dpart, ipart, out);
}

// Round 3
// 448.408 us; speedup vs baseline: 1.4603x; 1.4603x over previous
//
#include <hip/hip_runtime.h>
#include <math.h>

namespace {

constexpr int B = 2;
constexpr int F = 4096;      // triangles per batch
constexpr int Q = 16384;     // points per batch
constexpr int NP = B * Q;    // 32768 total points
constexpr int NCHUNK = 8;    // triangle chunks
constexpr int CF = F / NCHUNK;  // 512 triangles per chunk
constexpr int BLOCK = 256;

// output layout in d_out (float32):
//   dist    [B*Q]      at offset 0
//   closest [B*Q*3]    at offset NP
//   faces   [B*Q]      at offset NP + 3*NP  (written as float values)
constexpr int OFF_DIST = 0;
constexpr int OFF_CP = NP;
constexpr int OFF_FACE = NP + 3 * NP;

// ---------------- exact path (reference-bit-order, contract OFF) -----------

__device__ __forceinline__ float safediv(float num, float den) {
  #pragma clang fp contract(off)
  float d = (fabsf(den) > 1e-12f) ? den : 1.0f;
  return num / d;
}

__device__ __forceinline__ float clamp01(float x) {
  return fminf(fmaxf(x, 0.0f), 1.0f);
}

// Ericson region-based closest point on triangle, mirroring the JAX reference
// op-for-op (including the where/override order). Contract OFF inside.
__device__ __forceinline__ void closest_pt(
    float px, float py, float pz,
    float ax, float ay, float az,
    float bx, float by, float bz,
    float cx, float cy, float cz,
    float& rx, float& ry, float& rz) {
  #pragma clang fp contract(off)
  float abx = bx - ax, aby = by - ay, abz = bz - az;
  float acx = cx - ax, acy = cy - ay, acz = cz - az;
  float apx = px - ax, apy = py - ay, apz = pz - az;
  float d1 = (abx * apx + aby * apy) + abz * apz;
  float d2 = (acx * apx + acy * apy) + acz * apz;
  float bpx = px - bx, bpy = py - by, bpz = pz - bz;
  float d3 = (abx * bpx + aby * bpy) + abz * bpz;
  float d4 = (acx * bpx + acy * bpy) + acz * bpz;
  float cpx = px - cx, cpy = py - cy, cpz = pz - cz;
  float d5 = (abx * cpx + aby * cpy) + abz * cpz;
  float d6 = (acx * cpx + acy * cpy) + acz * cpz;

  float vc = d1 * d4 - d3 * d2;
  float vb = d5 * d2 - d1 * d6;
  float va = d3 * d6 - d5 * d4;

  float v_ab = clamp01(safediv(d1, d1 - d3));
  float w_ac = clamp01(safediv(d2, d2 - d6));
  float w_bc = clamp01(safediv(d4 - d3, (d4 - d3) + (d5 - d6)));

  float denom = (va + vb) + vc;
  float v = safediv(vb, denom);
  float w = safediv(vc, denom);

  float ox = ax + abx * v + acx * w;
  float oy = ay + aby * v + acy * w;
  float oz = az + abz * v + acz * w;

  bool m_bc = (va <= 0.0f) && (d4 - d3 >= 0.0f) && (d5 - d6 >= 0.0f);
  bool m_ac = (vb <= 0.0f) && (d2 >= 0.0f) && (d6 <= 0.0f);
  bool m_ab = (vc <= 0.0f) && (d1 >= 0.0f) && (d3 <= 0.0f);
  bool m_c  = (d6 >= 0.0f) && (d5 <= d6);
  bool m_b  = (d3 >= 0.0f) && (d4 <= d3);
  bool m_a  = (d1 <= 0.0f) && (d2 <= 0.0f);

  if (m_bc) { ox = bx + w_bc * (cx - bx); oy = by + w_bc * (cy - by); oz = bz + w_bc * (cz - bz); }
  if (m_ac) { ox = ax + w_ac * acx;       oy = ay + w_ac * acy;       oz = az + w_ac * acz; }
  if (m_ab) { ox = ax + v_ab * abx;       oy = ay + v_ab * aby;       oz = az + v_ab * abz; }
  if (m_c)  { ox = cx; oy = cy; oz = cz; }
  if (m_b)  { ox = bx; oy = by; oz = bz; }
  if (m_a)  { ox = ax; oy = ay; oz = az; }

  rx = ox; ry = oy; rz = oz;
}

// exact squared distance, reference op order
__device__ __forceinline__ float exact_d2(
    float px, float py, float pz, const float* __restrict__ g /*a,b,c*/) {
  #pragma clang fp contract(off)
  float rx, ry, rz;
  closest_pt(px, py, pz,
             g[0], g[1], g[2], g[3], g[4], g[5], g[6], g[7], g[8],
             rx, ry, rz);
  float dx = px - rx, dy = py - ry, dz = pz - rz;
  return (dx * dx + dy * dy) + dz * dz;
}

// ---------------- fast screening path (contract ON, rcp divides) -----------

__device__ __forceinline__ float frcp_s(float den) {
  float d = (fabsf(den) > 1e-12f) ? den : 1.0f;
  return __builtin_amdgcn_rcpf(d);
}

// fast d^2: tri stored as (a, ab, ac). Mathematically identical to the
// reference; rounding differs by ~1e-6 absolute (FMA + v_rcp).
__device__ __forceinline__ float fast_d2(
    float px, float py, float pz, const float* __restrict__ t) {
  #pragma clang fp contract(fast)
  float ax = t[0], ay = t[1], az = t[2];
  float abx = t[3], aby = t[4], abz = t[5];
  float acx = t[6], acy = t[7], acz = t[8];

  float apx = px - ax, apy = py - ay, apz = pz - az;
  float d1 = apx * abx + apy * aby + apz * abz;
  float d2 = apx * acx + apy * acy + apz * acz;
  float bpx = apx - abx, bpy = apy - aby, bpz = apz - abz;   // p - b
  float d3 = bpx * abx + bpy * aby + bpz * abz;
  float d4 = bpx * acx + bpy * acy + bpz * acz;
  float cpx = apx - acx, cpy = apy - acy, cpz = apz - acz;   // p - c
  float d5 = cpx * abx + cpy * aby + cpz * abz;
  float d6 = cpx * acx + cpy * acy + cpz * acz;

  float vc = d1 * d4 - d3 * d2;
  float vb = d5 * d2 - d1 * d6;
  float va = d3 * d6 - d5 * d4;
  float t43 = d4 - d3, t56 = d5 - d6;

  float v_ab = clamp01(d1 * frcp_s(d1 - d3));
  float w_ac = clamp01(d2 * frcp_s(d2 - d6));
  float w_bc = clamp01(t43 * frcp_s(t43 + t56));
  float r = frcp_s((va + vb) + vc);
  float v = vb * r;
  float w = vc * r;

  bool m_bc = (va <= 0.0f) & (t43 >= 0.0f) & (t56 >= 0.0f);
  bool m_ac = (vb <= 0.0f) & (d2 >= 0.0f) & (d6 <= 0.0f);
  bool m_ab = (vc <= 0.0f) & (d1 >= 0.0f) & (d3 <= 0.0f);
  bool m_c  = (d6 >= 0.0f) & (d5 <= d6);
  bool m_b  = (d3 >= 0.0f) & (d4 <= d3);
  bool m_a  = (d1 <= 0.0f) & (d2 <= 0.0f);

  // same precedence as reference: later overrides earlier
  v = m_bc ? (1.0f - w_bc) : v;  w = m_bc ? w_bc : w;
  v = m_ac ? 0.0f : v;           w = m_ac ? w_ac : w;
  v = m_ab ? v_ab : v;           w = m_ab ? 0.0f : w;
  v = m_c  ? 0.0f : v;           w = m_c  ? 1.0f : w;
  v = m_b  ? 1.0f : v;           w = m_b  ? 0.0f : w;
  v = m_a  ? 0.0f : v;           w = m_a  ? 0.0f : w;

  float qx = ax + v * abx + w * acx;
  float qy = ay + v * aby + w * acy;
  float qz = az + v * abz + w * acz;
  float dx = px - qx, dy = py - qy, dz = pz - qz;
  return dx * dx + dy * dy + dz * dz;
}

// ---------------- kernels --------------------------------------------------

__global__ __launch_bounds__(BLOCK) void bvh_partial(
    const float* __restrict__ tris,   // [B, F, 3, 3]
    const float* __restrict__ pts,    // [B, Q, 3]
    float* __restrict__ dbest,        // [NCHUNK, NP] exact d2 of chunk winner
    int* __restrict__ ibest) {        // [NCHUNK, NP] global tri idx
  __shared__ float s_tri[CF * 9];     // (a, ab, ac) per tri, 18 KiB

  const int chunk = blockIdx.y;
  const int gpt = blockIdx.x * BLOCK + threadIdx.x;  // 0 .. NP-1
  const int batch = gpt / Q;  // uniform per block (BLOCK divides Q)
  const int tri0 = chunk * CF;

  // stage (a, b-a, c-a) into LDS
  for (int t = threadIdx.x; t < CF; t += BLOCK) {
    const float* g = tris + ((size_t)batch * F + tri0 + t) * 9;
    float ax = g[0], ay = g[1], az = g[2];
    float bx = g[3], by = g[4], bz = g[5];
    float cx = g[6], cy = g[7], cz = g[8];
    float* s = &s_tri[t * 9];
    s[0] = ax;      s[1] = ay;      s[2] = az;
    s[3] = bx - ax; s[4] = by - ay; s[5] = bz - az;
    s[6] = cx - ax; s[7] = cy - ay; s[8] = cz - az;
  }
  __syncthreads();

  const float px = pts[gpt * 3 + 0];
  const float py = pts[gpt * 3 + 1];
  const float pz = pts[gpt * 3 + 2];

  // fast screen: keep top-3 smallest fast d2 (value-sorted m1<=m2<=m3)
  float m1 = INFINITY, m2 = INFINITY, m3 = INFINITY;
  int i1 = 0, i2 = 0, i3 = 0;
  for (int t = 0; t < CF; ++t) {
    float d = fast_d2(px, py, pz, &s_tri[t * 9]);
    bool b1 = d < m1, b2 = d < m2, b3 = d < m3;
    m3 = b2 ? m2 : (b3 ? d : m3);  i3 = b2 ? i2 : (b3 ? t : i3);
    m2 = b1 ? m1 : (b2 ? d : m2);  i2 = b1 ? i1 : (b2 ? t : i2);
    m1 = b1 ? d  : m1;             i1 = b1 ? t  : i1;
  }

  // sort candidate indices ascending (first-occurrence argmin semantics)
  int ia = i1, ib = i2, ic = i3, tmp;
  if (ia > ib) { tmp = ia; ia = ib; ib = tmp; }
  if (ib > ic) { tmp = ib; ib = ic; ic = tmp; }
  if (ia > ib) { tmp = ia; ia = ib; ib = tmp; }

  // exact re-evaluation of the 3 candidates, reference bit order
  const float* tb = tris + (size_t)batch * F * 9;
  float be;
  int bi = ia;
  be = exact_d2(px, py, pz, tb + (size_t)(tri0 + ia) * 9);
  {
    float d = exact_d2(px, py, pz, tb + (size_t)(tri0 + ib) * 9);
    if (d < be) { be = d; bi = ib; }
  }
  {
    float d = exact_d2(px, py, pz, tb + (size_t)(tri0 + ic) * 9);
    if (d < be) { be = d; bi = ic; }
  }

  dbest[chunk * NP + gpt] = be;
  ibest[chunk * NP + gpt] = tri0 + bi;
}

__global__ __launch_bounds__(BLOCK) void bvh_reduce(
    const float* __restrict__ tris,
    const float* __restrict__ pts,
    const float* __restrict__ dbest,
    const int* __restrict__ ibest,
    float* __restrict__ out) {
  const int gpt = blockIdx.x * BLOCK + threadIdx.x;
  if (gpt >= NP) return;

  float best = INFINITY;
  int bi = 0;
  for (int c = 0; c < NCHUNK; ++c) {   // ascending chunk order: first-occurrence on ties
    float d = dbest[c * NP + gpt];
    if (d < best) { best = d; bi = ibest[c * NP + gpt]; }
  }

  const int batch = gpt / Q;
  const float px = pts[gpt * 3 + 0];
  const float py = pts[gpt * 3 + 1];
  const float pz = pts[gpt * 3 + 2];

  const float* tr = tris + ((size_t)batch * F + bi) * 9;
  float rx, ry, rz;
  closest_pt(px, py, pz,
             tr[0], tr[1], tr[2],
             tr[3], tr[4], tr[5],
             tr[6], tr[7], tr[8],
             rx, ry, rz);

  out[OFF_DIST + gpt] = best;
  out[OFF_CP + gpt * 3 + 0] = rx;
  out[OFF_CP + gpt * 3 + 1] = ry;
  out[OFF_CP + gpt * 3 + 2] = rz;
  out[OFF_FACE + gpt] = (float)bi;   // harness reads whole out buffer as f32
}

}  // namespace

extern "C" void kernel_launch(void* const* d_in, const int* in_sizes, int n_in,
                              void* d_out, int out_size, void* d_ws, size_t ws_size,
                              hipStream_t stream) {
  const float* tris = (const float*)d_in[0];
  const float* pts  = (const float*)d_in[1];
  float* out = (float*)d_out;

  float* dbest = (float*)d_ws;                                     // 1 MiB
  int* ibest = (int*)((char*)d_ws + sizeof(float) * NCHUNK * NP);  // 1 MiB

  dim3 grid1(NP / BLOCK, NCHUNK);   // 128 x 8 blocks
  bvh_partial<<<grid1, BLOCK, 0, stream>>>(tris, pts, dbest, ibest);

  dim3 grid2((NP + BLOCK - 1) / BLOCK);
  bvh_reduce<<<grid2, BLOCK, 0, stream>>>(tris, pts, dbest, ibest, out);
}

// Round 5
// 338.555 us; speedup vs baseline: 1.9341x; 1.3245x over previous
//
#include <hip/hip_runtime.h>
#include <math.h>

namespace {

constexpr int B = 2;
constexpr int F = 4096;      // triangles per batch
constexpr int Q = 16384;     // points per batch
constexpr int NP = B * Q;    // 32768 total points
constexpr int NCHUNK = 8;    // triangle chunks
constexpr int CF = F / NCHUNK;  // 512 triangles per chunk
constexpr int BLOCK = 256;

// output layout in d_out (float32): dist [NP], closest [NP,3], faces [NP]
constexpr int OFF_DIST = 0;
constexpr int OFF_CP = NP;
constexpr int OFF_FACE = 4 * NP;

// ---------------- exact path (reference-bit-order, contract OFF) -----------

__device__ __forceinline__ float safediv(float num, float den) {
  #pragma clang fp contract(off)
  float d = (fabsf(den) > 1e-12f) ? den : 1.0f;
  return num / d;
}

__device__ __forceinline__ float clamp01(float x) {
  return fminf(fmaxf(x, 0.0f), 1.0f);
}

// Ericson region-based closest point on triangle, mirroring the JAX reference
// op-for-op (including the where/override order). Contract OFF inside.
__device__ __forceinline__ void closest_pt(
    float px, float py, float pz,
    float ax, float ay, float az,
    float bx, float by, float bz,
    float cx, float cy, float cz,
    float& rx, float& ry, float& rz) {
  #pragma clang fp contract(off)
  float abx = bx - ax, aby = by - ay, abz = bz - az;
  float acx = cx - ax, acy = cy - ay, acz = cz - az;
  float apx = px - ax, apy = py - ay, apz = pz - az;
  float d1 = (abx * apx + aby * apy) + abz * apz;
  float d2 = (acx * apx + acy * apy) + acz * apz;
  float bpx = px - bx, bpy = py - by, bpz = pz - bz;
  float d3 = (abx * bpx + aby * bpy) + abz * bpz;
  float d4 = (acx * bpx + acy * bpy) + acz * bpz;
  float cpx = px - cx, cpy = py - cy, cpz = pz - cz;
  float d5 = (abx * cpx + aby * cpy) + abz * cpz;
  float d6 = (acx * cpx + acy * cpy) + acz * cpz;

  float vc = d1 * d4 - d3 * d2;
  float vb = d5 * d2 - d1 * d6;
  float va = d3 * d6 - d5 * d4;

  float v_ab = clamp01(safediv(d1, d1 - d3));
  float w_ac = clamp01(safediv(d2, d2 - d6));
  float w_bc = clamp01(safediv(d4 - d3, (d4 - d3) + (d5 - d6)));

  float denom = (va + vb) + vc;
  float v = safediv(vb, denom);
  float w = safediv(vc, denom);

  float ox = ax + abx * v + acx * w;
  float oy = ay + aby * v + acy * w;
  float oz = az + abz * v + acz * w;

  bool m_bc = (va <= 0.0f) && (d4 - d3 >= 0.0f) && (d5 - d6 >= 0.0f);
  bool m_ac = (vb <= 0.0f) && (d2 >= 0.0f) && (d6 <= 0.0f);
  bool m_ab = (vc <= 0.0f) && (d1 >= 0.0f) && (d3 <= 0.0f);
  bool m_c  = (d6 >= 0.0f) && (d5 <= d6);
  bool m_b  = (d3 >= 0.0f) && (d4 <= d3);
  bool m_a  = (d1 <= 0.0f) && (d2 <= 0.0f);

  if (m_bc) { ox = bx + w_bc * (cx - bx); oy = by + w_bc * (cy - by); oz = bz + w_bc * (cz - bz); }
  if (m_ac) { ox = ax + w_ac * acx;       oy = ay + w_ac * acy;       oz = az + w_ac * acz; }
  if (m_ab) { ox = ax + v_ab * abx;       oy = ay + v_ab * aby;       oz = az + v_ab * abz; }
  if (m_c)  { ox = cx; oy = cy; oz = cz; }
  if (m_b)  { ox = bx; oy = by; oz = bz; }
  if (m_a)  { ox = ax; oy = ay; oz = az; }

  rx = ox; ry = oy; rz = oz;
}

__device__ __forceinline__ float exact_d2(
    float px, float py, float pz, const float* __restrict__ g /*a,b,c*/) {
  #pragma clang fp contract(off)
  float rx, ry, rz;
  closest_pt(px, py, pz,
             g[0], g[1], g[2], g[3], g[4], g[5], g[6], g[7], g[8],
             rx, ry, rz);
  float dx = px - rx, dy = py - ry, dz = pz - rz;
  return (dx * dx + dy * dy) + dz * dz;
}

// ---------------- kernels --------------------------------------------------

// LDS record per triangle (16 floats = 4x float4):
//  [ax,ay,az,abx][aby,abz,acx,acy][acz,aa,bb,abac][raa,rbb,rcc,rdenom]
__global__ __launch_bounds__(BLOCK) void bvh_partial(
    const float* __restrict__ tris,   // [B, F, 3, 3]
    const float* __restrict__ pts,    // [B, Q, 3]
    float* __restrict__ dbest,        // [NCHUNK, NP]
    int* __restrict__ ibest) {        // [NCHUNK, NP]
  __shared__ float s_tri[CF][16];     // 32 KiB

  const int chunk = blockIdx.y;
  const int gpt = blockIdx.x * BLOCK + threadIdx.x;  // 0 .. NP-1
  const int batch = gpt / Q;  // uniform per block (BLOCK divides Q)
  const int tri0 = chunk * CF;
  const float* tb = tris + (size_t)batch * F * 9;

  // stage triangle + Gram precompute into LDS
  for (int t = threadIdx.x; t < CF; t += BLOCK) {
    const float* g = tb + (size_t)(tri0 + t) * 9;
    float ax = g[0], ay = g[1], az = g[2];
    float abx = g[3] - ax, aby = g[4] - ay, abz = g[5] - az;
    float acx = g[6] - ax, acy = g[7] - ay, acz = g[8] - az;
    float aa   = abx * abx + aby * aby + abz * abz;   // d1-d3 denominator
    float bb   = acx * acx + acy * acy + acz * acz;   // d2-d6 denominator
    float abac = abx * acx + aby * acy + abz * acz;
    float bcx = acx - abx, bcy = acy - aby, bcz = acz - abz;
    float cc   = bcx * bcx + bcy * bcy + bcz * bcz;   // (d4-d3)+(d5-d6) denom
    float nx = aby * acz - abz * acy;
    float ny = abz * acx - abx * acz;
    float nz = abx * acy - aby * acx;
    float n2 = nx * nx + ny * ny + nz * nz;           // va+vb+vc
    float raa = (aa > 1e-12f) ? 1.0f / aa : 1.0f;     // safediv semantics
    float rbb = (bb > 1e-12f) ? 1.0f / bb : 1.0f;
    float rcc = (cc > 1e-12f) ? 1.0f / cc : 1.0f;
    float rdn = (n2 > 1e-12f) ? 1.0f / n2 : 1.0f;
    float4* s = (float4*)s_tri[t];
    s[0] = make_float4(ax, ay, az, abx);
    s[1] = make_float4(aby, abz, acx, acy);
    s[2] = make_float4(acz, aa, bb, abac);
    s[3] = make_float4(raa, rbb, rcc, rdn);
  }
  __syncthreads();

  const float px = pts[gpt * 3 + 0];
  const float py = pts[gpt * 3 + 1];
  const float pz = pts[gpt * 3 + 2];

  // fast screen: keep top-3 smallest screen-d2 (value-sorted m1<=m2<=m3)
  float m1 = INFINITY, m2 = INFINITY, m3 = INFINITY;
  int i1 = 0, i2 = 0, i3 = 0;

  {
    #pragma clang fp contract(fast)
    for (int t = 0; t < CF; ++t) {
      const float4* sv = (const float4*)s_tri[t];  // uniform addr -> broadcast
      float4 A0 = sv[0], A1 = sv[1], A2 = sv[2], A3 = sv[3];
      float ax = A0.x, ay = A0.y, az = A0.z;
      float abx = A0.w, aby = A1.x, abz = A1.y;
      float acx = A1.z, acy = A1.w, acz = A2.x;
      float aa = A2.y, bb = A2.z, abac = A2.w;
      float raa = A3.x, rbb = A3.y, rcc = A3.z, rdn = A3.w;

      float apx = px - ax, apy = py - ay, apz = pz - az;
      float d1 = apx * abx + apy * aby + apz * abz;
      float d2 = apx * acx + apy * acy + apz * acz;
      float ap2 = apx * apx + apy * apy + apz * apz;
      float d3 = d1 - aa;
      float d6 = d2 - bb;
      float d4 = d2 - abac;
      float d5 = d1 - abac;
      float t43 = d4 - d3, t56 = d5 - d6;

      float vc = d1 * d4 - d3 * d2;
      float vb = d5 * d2 - d1 * d6;
      float va = d3 * d6 - d5 * d4;

      float v_ab = clamp01(d1 * raa);
      float w_ac = clamp01(d2 * rbb);
      float w_bc = clamp01(t43 * rcc);
      float v = vb * rdn;
      float w = vc * rdn;

      bool m_bc = (va <= 0.0f) & (t43 >= 0.0f) & (t56 >= 0.0f);
      bool m_ac = (vb <= 0.0f) & (d2 >= 0.0f) & (d6 <= 0.0f);
      bool m_ab = (vc <= 0.0f) & (d1 >= 0.0f) & (d3 <= 0.0f);
      bool m_c  = (d6 >= 0.0f) & (d5 <= d6);
      bool m_b  = (d3 >= 0.0f) & (d4 <= d3);
      bool m_a  = (d1 <= 0.0f) & (d2 <= 0.0f);

      float omw = 1.0f - w_bc;
      v = m_bc ? omw  : v;   w = m_bc ? w_bc : w;
      v = m_ac ? 0.0f : v;   w = m_ac ? w_ac : w;
      v = m_ab ? v_ab : v;   w = m_ab ? 0.0f : w;
      v = m_c  ? 0.0f : v;   w = m_c  ? 1.0f : w;
      v = m_b  ? 1.0f : v;   w = m_b  ? 0.0f : w;
      v = m_a  ? 0.0f : v;   w = m_a  ? 0.0f : w;

      // d2 via barycentric quadratic form (no closest-point reconstruction)
      float td1 = d1 + d1, td2 = d2 + d2;
      float h1 = v * aa + (w * abac - td1);
      float h2 = w * bb + (v * abac - td2);
      float d = ap2 + (v * h1 + w * h2);

      bool b1 = d < m1, b2 = d < m2, b3 = d < m3;
      m3 = b2 ? m2 : (b3 ? d : m3);  i3 = b2 ? i2 : (b3 ? t : i3);
      m2 = b1 ? m1 : (b2 ? d : m2);  i2 = b1 ? i1 : (b2 ? t : i2);
      m1 = b1 ? d  : m1;             i1 = b1 ? t  : i1;
    }
  }

  // sort candidate indices ascending (first-occurrence argmin semantics)
  int ia = i1, ib = i2, ic = i3, tmp;
  if (ia > ib) { tmp = ia; ia = ib; ib = tmp; }
  if (ib > ic) { tmp = ib; ib = ic; ic = tmp; }
  if (ia > ib) { tmp = ia; ia = ib; ib = tmp; }

  // exact re-evaluation of the 3 candidates, reference bit order
  float be;
  int bi = ia;
  be = exact_d2(px, py, pz, tb + (size_t)(tri0 + ia) * 9);
  {
    float d = exact_d2(px, py, pz, tb + (size_t)(tri0 + ib) * 9);
    if (d < be) { be = d; bi = ib; }
  }
  {
    float d = exact_d2(px, py, pz, tb + (size_t)(tri0 + ic) * 9);
    if (d < be) { be = d; bi = ic; }
  }

  dbest[chunk * NP + gpt] = be;
  ibest[chunk * NP + gpt] = tri0 + bi;
}

__global__ __launch_bounds__(BLOCK) void bvh_reduce(
    const float* __restrict__ tris,
    const float* __restrict__ pts,
    const float* __restrict__ dbest,
    const int* __restrict__ ibest,
    float* __restrict__ out) {
  const int gpt = blockIdx.x * BLOCK + threadIdx.x;
  if (gpt >= NP) return;

  float best = INFINITY;
  int bi = 0;
  for (int c = 0; c < NCHUNK; ++c) {   // ascending chunk order: first-occurrence on ties
    float d = dbest[c * NP + gpt];
    if (d < best) { best = d; bi = ibest[c * NP + gpt]; }
  }

  const int batch = gpt / Q;
  const float px = pts[gpt * 3 + 0];
  const float py = pts[gpt * 3 + 1];
  const float pz = pts[gpt * 3 + 2];

  const float* tr = tris + ((size_t)batch * F + bi) * 9;
  float rx, ry, rz;
  closest_pt(px, py, pz,
             tr[0], tr[1], tr[2],
             tr[3], tr[4], tr[5],
             tr[6], tr[7], tr[8],
             rx, ry, rz);

  out[OFF_DIST + gpt] = best;
  out[OFF_CP + gpt * 3 + 0] = rx;
  out[OFF_CP + gpt * 3 + 1] = ry;
  out[OFF_CP + gpt * 3 + 2] = rz;
  out[OFF_FACE + gpt] = (float)bi;   // harness reads whole out buffer as f32
}

}  // namespace

extern "C" void kernel_launch(void* const* d_in, const int* in_sizes, int n_in,
                              void* d_out, int out_size, void* d_ws, size_t ws_size,
                              hipStream_t stream) {
  const float* tris = (const float*)d_in[0];
  const float* pts  = (const float*)d_in[1];
  float* out = (float*)d_out;

  float* dbest = (float*)d_ws;                                     // 1 MiB
  int* ibest = (int*)((char*)d_ws + sizeof(float) * NCHUNK * NP);  // 1 MiB

  dim3 grid1(NP / BLOCK, NCHUNK);   // 128 x 8 blocks = 4 blocks/CU
  bvh_partial<<<grid1, BLOCK, 0, stream>>>(tris, pts, dbest, ibest);

  dim3 grid2((NP + BLOCK - 1) / BLOCK);
  bvh_reduce<<<grid2, BLOCK, 0, stream>>>(tris, pts, dbest, ibest, out);
}

// Round 6
// 225.259 us; speedup vs baseline: 2.9069x; 1.5030x over previous
//
#include <hip/hip_runtime.h>
#include <math.h>

namespace {

constexpr int B = 2;
constexpr int F = 4096;      // triangles per batch
constexpr int Q = 16384;     // points per batch
constexpr int NP = B * Q;    // 32768 total points
constexpr int NCHUNK = 8;    // triangle chunks
constexpr int CF = F / NCHUNK;  // 512 triangles per chunk
constexpr int BLOCK = 256;

// output layout in d_out (float32): dist [NP], closest [NP,3], faces [NP]
constexpr int OFF_DIST = 0;
constexpr int OFF_CP = NP;
constexpr int OFF_FACE = 4 * NP;

// ---------------- exact path (reference-bit-order, contract OFF) -----------

__device__ __forceinline__ float safediv(float num, float den) {
  #pragma clang fp contract(off)
  float d = (fabsf(den) > 1e-12f) ? den : 1.0f;
  return num / d;
}

__device__ __forceinline__ float clamp01(float x) {
  return fminf(fmaxf(x, 0.0f), 1.0f);
}

// Ericson region-based closest point on triangle, mirroring the JAX reference
// op-for-op (including the where/override order). Contract OFF inside.
__device__ __forceinline__ void closest_pt(
    float px, float py, float pz,
    float ax, float ay, float az,
    float bx, float by, float bz,
    float cx, float cy, float cz,
    float& rx, float& ry, float& rz) {
  #pragma clang fp contract(off)
  float abx = bx - ax, aby = by - ay, abz = bz - az;
  float acx = cx - ax, acy = cy - ay, acz = cz - az;
  float apx = px - ax, apy = py - ay, apz = pz - az;
  float d1 = (abx * apx + aby * apy) + abz * apz;
  float d2 = (acx * apx + acy * apy) + acz * apz;
  float bpx = px - bx, bpy = py - by, bpz = pz - bz;
  float d3 = (abx * bpx + aby * bpy) + abz * bpz;
  float d4 = (acx * bpx + acy * bpy) + acz * bpz;
  float cpx = px - cx, cpy = py - cy, cpz = pz - cz;
  float d5 = (abx * cpx + aby * cpy) + abz * cpz;
  float d6 = (acx * cpx + acy * cpy) + acz * cpz;

  float vc = d1 * d4 - d3 * d2;
  float vb = d5 * d2 - d1 * d6;
  float va = d3 * d6 - d5 * d4;

  float v_ab = clamp01(safediv(d1, d1 - d3));
  float w_ac = clamp01(safediv(d2, d2 - d6));
  float w_bc = clamp01(safediv(d4 - d3, (d4 - d3) + (d5 - d6)));

  float denom = (va + vb) + vc;
  float v = safediv(vb, denom);
  float w = safediv(vc, denom);

  float ox = ax + abx * v + acx * w;
  float oy = ay + aby * v + acy * w;
  float oz = az + abz * v + acz * w;

  bool m_bc = (va <= 0.0f) && (d4 - d3 >= 0.0f) && (d5 - d6 >= 0.0f);
  bool m_ac = (vb <= 0.0f) && (d2 >= 0.0f) && (d6 <= 0.0f);
  bool m_ab = (vc <= 0.0f) && (d1 >= 0.0f) && (d3 <= 0.0f);
  bool m_c  = (d6 >= 0.0f) && (d5 <= d6);
  bool m_b  = (d3 >= 0.0f) && (d4 <= d3);
  bool m_a  = (d1 <= 0.0f) && (d2 <= 0.0f);

  if (m_bc) { ox = bx + w_bc * (cx - bx); oy = by + w_bc * (cy - by); oz = bz + w_bc * (cz - bz); }
  if (m_ac) { ox = ax + w_ac * acx;       oy = ay + w_ac * acy;       oz = az + w_ac * acz; }
  if (m_ab) { ox = ax + v_ab * abx;       oy = ay + v_ab * aby;       oz = az + v_ab * abz; }
  if (m_c)  { ox = cx; oy = cy; oz = cz; }
  if (m_b)  { ox = bx; oy = by; oz = bz; }
  if (m_a)  { ox = ax; oy = ay; oz = az; }

  rx = ox; ry = oy; rz = oz;
}

__device__ __forceinline__ float exact_d2(
    float px, float py, float pz, const float* __restrict__ g /*a,b,c*/) {
  #pragma clang fp contract(off)
  float rx, ry, rz;
  closest_pt(px, py, pz,
             g[0], g[1], g[2], g[3], g[4], g[5], g[6], g[7], g[8],
             rx, ry, rz);
  float dx = px - rx, dy = py - ry, dz = pz - rz;
  return (dx * dx + dy * dy) + dz * dz;
}

// ---------------- kernels --------------------------------------------------

// LDS record per triangle: 20 floats = 5x float4
//  [abx,aby,abz,c1] [acx,acy,acz,c2] [m2ax,m2ay,m2az,caa2] [aa,bb,abac,cc]
//  [raa,rbb,rcc,rdn]
// where c1=-(a.ab), c2=-(a.ac), m2a=-2a, caa2=|a|^2.
// Screen computes d^2 - |p|^2 (per-lane constant offset: ranking-invariant).
__global__ __launch_bounds__(BLOCK, 4) void bvh_partial(
    const float* __restrict__ tris,   // [B, F, 3, 3]
    const float* __restrict__ pts,    // [B, Q, 3]
    float* __restrict__ dbest,        // [NCHUNK, NP]
    int* __restrict__ ibest) {        // [NCHUNK, NP]
  __shared__ float s_tri[CF][20];     // 40 KiB

  const int chunk = blockIdx.y;
  const int gpt = blockIdx.x * BLOCK + threadIdx.x;  // 0 .. NP-1
  const int batch = gpt / Q;  // uniform per block (BLOCK divides Q)
  const int tri0 = chunk * CF;
  const float* tb = tris + (size_t)batch * F * 9;

  // stage triangle Gram precompute into LDS
  for (int t = threadIdx.x; t < CF; t += BLOCK) {
    const float* g = tb + (size_t)(tri0 + t) * 9;
    float ax = g[0], ay = g[1], az = g[2];
    float abx = g[3] - ax, aby = g[4] - ay, abz = g[5] - az;
    float acx = g[6] - ax, acy = g[7] - ay, acz = g[8] - az;
    float aa   = abx * abx + aby * aby + abz * abz;
    float bb   = acx * acx + acy * acy + acz * acz;
    float abac = abx * acx + aby * acy + abz * acz;
    float bcx = acx - abx, bcy = acy - aby, bcz = acz - abz;
    float cc   = bcx * bcx + bcy * bcy + bcz * bcz;
    float nx = aby * acz - abz * acy;
    float ny = abz * acx - abx * acz;
    float nz = abx * acy - aby * acx;
    float n2 = nx * nx + ny * ny + nz * nz;           // |ab x ac|^2 = va+vb+vc
    float raa = (aa > 1e-12f) ? 1.0f / aa : 1.0f;     // safediv-style guards
    float rbb = (bb > 1e-12f) ? 1.0f / bb : 1.0f;
    float rcc = (cc > 1e-12f) ? 1.0f / cc : 1.0f;
    float rdn = (n2 > 1e-12f) ? 1.0f / n2 : 1.0f;
    float c1 = -(ax * abx + ay * aby + az * abz);
    float c2 = -(ax * acx + ay * acy + az * acz);
    float caa2 = ax * ax + ay * ay + az * az;
    float4* s = (float4*)s_tri[t];
    s[0] = make_float4(abx, aby, abz, c1);
    s[1] = make_float4(acx, acy, acz, c2);
    s[2] = make_float4(-2.0f * ax, -2.0f * ay, -2.0f * az, caa2);
    s[3] = make_float4(aa, bb, abac, cc);
    s[4] = make_float4(raa, rbb, rcc, rdn);
  }
  __syncthreads();

  const float px = pts[gpt * 3 + 0];
  const float py = pts[gpt * 3 + 1];
  const float pz = pts[gpt * 3 + 2];

  // fast screen: keep top-3 smallest screen values (value-sorted m1<=m2<=m3)
  float m1 = INFINITY, m2 = INFINITY, m3 = INFINITY;
  int i1 = 0, i2 = 0, i3 = 0;

  {
    #pragma clang fp contract(fast)
    #pragma unroll 2
    for (int t = 0; t < CF; ++t) {
      const float4* sv = (const float4*)s_tri[t];  // uniform addr -> broadcast
      float4 A0 = sv[0], A1 = sv[1], A2 = sv[2], A3 = sv[3], A4 = sv[4];

      // affine forms in p
      float d1  = fmaf(px, A0.x, fmaf(py, A0.y, fmaf(pz, A0.z, A0.w)));
      float d2  = fmaf(px, A1.x, fmaf(py, A1.y, fmaf(pz, A1.z, A1.w)));
      float ap2 = fmaf(px, A2.x, fmaf(py, A2.y, fmaf(pz, A2.z, A2.w))); // |ap|^2-|p|^2
      float aa = A3.x, bb = A3.y, abac = A3.z, cc = A3.w;
      float raa = A4.x, rbb = A4.y, rcc = A4.z, rdn = A4.w;

      float d3 = d1 - aa, d6 = d2 - bb, d4 = d2 - abac, d5 = d1 - abac;
      float va = d3 * d6 - d5 * d4;
      float vb = d5 * d2 - d1 * d6;
      float vc = d1 * d4 - d3 * d2;
      float td1 = d1 + d1, td2 = d2 + d2;

      // interior distance via barycentric quadratic form
      float v = vb * rdn, w = vc * rdn;
      float h1 = fmaf(v, aa, fmaf(w, abac, -td1));
      float h2 = fmaf(w, bb, fmaf(v, abac, -td2));
      float dint = ap2 + fmaf(v, h1, w * h2);

      // three edge-segment distances (exact boundary distance)
      float tab = clamp01(d1 * raa);
      float sab = fmaf(-tab, fmaf(-tab, aa, td1), ap2);
      float tac = clamp01(d2 * rbb);
      float sac = fmaf(-tac, fmaf(-tac, bb, td2), ap2);
      float t43 = d4 - d3;
      float bp2 = (ap2 - td1) + aa;
      float tbc = clamp01(t43 * rcc);
      float sbc = fmaf(-tbc, fmaf(-tbc, cc, t43 + t43), bp2);

      float dseg = fminf(fminf(sab, sac), sbc);    // v_min3_f32
      bool inter = (va > 0.0f) & (vb > 0.0f) & (vc > 0.0f);
      float d = inter ? dint : dseg;

      bool b1 = d < m1, b2 = d < m2, b3 = d < m3;
      m3 = b2 ? m2 : (b3 ? d : m3);  i3 = b2 ? i2 : (b3 ? t : i3);
      m2 = b1 ? m1 : (b2 ? d : m2);  i2 = b1 ? i1 : (b2 ? t : i2);
      m1 = b1 ? d  : m1;             i1 = b1 ? t  : i1;
    }
  }

  // sort candidate indices ascending (first-occurrence argmin semantics)
  int ia = i1, ib = i2, ic = i3, tmp;
  if (ia > ib) { tmp = ia; ia = ib; ib = tmp; }
  if (ib > ic) { tmp = ib; ib = ic; ic = tmp; }
  if (ia > ib) { tmp = ia; ia = ib; ib = tmp; }

  // exact re-evaluation of the 3 candidates, reference bit order
  float be;
  int bi = ia;
  be = exact_d2(px, py, pz, tb + (size_t)(tri0 + ia) * 9);
  {
    float d = exact_d2(px, py, pz, tb + (size_t)(tri0 + ib) * 9);
    if (d < be) { be = d; bi = ib; }
  }
  {
    float d = exact_d2(px, py, pz, tb + (size_t)(tri0 + ic) * 9);
    if (d < be) { be = d; bi = ic; }
  }

  dbest[chunk * NP + gpt] = be;
  ibest[chunk * NP + gpt] = tri0 + bi;
}

__global__ __launch_bounds__(BLOCK) void bvh_reduce(
    const float* __restrict__ tris,
    const float* __restrict__ pts,
    const float* __restrict__ dbest,
    const int* __restrict__ ibest,
    float* __restrict__ out) {
  const int gpt = blockIdx.x * BLOCK + threadIdx.x;
  if (gpt >= NP) return;

  float best = INFINITY;
  int bi = 0;
  for (int c = 0; c < NCHUNK; ++c) {   // ascending chunk order: first-occurrence on ties
    float d = dbest[c * NP + gpt];
    if (d < best) { best = d; bi = ibest[c * NP + gpt]; }
  }

  const int batch = gpt / Q;
  const float px = pts[gpt * 3 + 0];
  const float py = pts[gpt * 3 + 1];
  const float pz = pts[gpt * 3 + 2];

  const float* tr = tris + ((size_t)batch * F + bi) * 9;
  float rx, ry, rz;
  closest_pt(px, py, pz,
             tr[0], tr[1], tr[2],
             tr[3], tr[4], tr[5],
             tr[6], tr[7], tr[8],
             rx, ry, rz);

  out[OFF_DIST + gpt] = best;
  out[OFF_CP + gpt * 3 + 0] = rx;
  out[OFF_CP + gpt * 3 + 1] = ry;
  out[OFF_CP + gpt * 3 + 2] = rz;
  out[OFF_FACE + gpt] = (float)bi;   // harness reads whole out buffer as f32
}

}  // namespace

extern "C" void kernel_launch(void* const* d_in, const int* in_sizes, int n_in,
                              void* d_out, int out_size, void* d_ws, size_t ws_size,
                              hipStream_t stream) {
  const float* tris = (const float*)d_in[0];
  const float* pts  = (const float*)d_in[1];
  float* out = (float*)d_out;

  float* dbest = (float*)d_ws;                                     // 1 MiB
  int* ibest = (int*)((char*)d_ws + sizeof(float) * NCHUNK * NP);  // 1 MiB

  dim3 grid1(NP / BLOCK, NCHUNK);   // 128 x 8 blocks = 4 blocks/CU
  bvh_partial<<<grid1, BLOCK, 0, stream>>>(tris, pts, dbest, ibest);

  dim3 grid2((NP + BLOCK - 1) / BLOCK);
  bvh_reduce<<<grid2, BLOCK, 0, stream>>>(tris, pts, dbest, ibest, out);
}